// Round 2
// baseline (148.590 us; speedup 1.0000x reference)
//
#include <hip/hip_runtime.h>

#define DIM 4096
using F2 = float2;

// R15: ONE WAVE PER BLOCK (64 threads), amp[64]/lane = full 4096-amp state.
// R13/R14 post-mortem: dur flat under LDS halving, occupancy stuck ~16% ->
// bound by per-block critical path (barrier-locked 2-wave blocks), not
// residency. Fix: 6-bit register layouts make every gate register-internal
// and every transpose WAVE-INTERNAL (same-wave LDS round trip, in-order DS,
// no cross-wave barrier waits). __syncthreads() remain only as single-wave
// lgkmcnt drains (cheap) guarding ST->LD RAW and LD->ST WAR on the shared
// 16 KB buffer. Gate math / coef layout / prep kernel: identical to R13/R14.
//
// Layouts (qubit q <-> address bit 11-q; lane = 6 bits, reg = 6 bits):
//  A: reg r = a[11:6]                lane = a[5:0]
//     masks q0:32 q1:16 q2:8 q3:4 q4:2 q5:1
//  B: r0=a6, r[5:1]=a[5:1]          lane0=a0, lane[5:1]=a[11:7]
//     masks q5:1 q6:32 q7:16 q8:8 q9:4 q10:2
//  C: r0=a10,r1=a11,r2=a0,r3=a3,r4=a1,r5=a2   lane = a[9:4]
//     masks q8:8 q9:32 q10:16 q11:4 q0:2 q1:1
// Transitions (shared addr bit = SAME register bit both sides -> round h
// stores and reloads exactly the register set {r : (r&SB)==h*SB}):
//  T1 A->B, T4 B->A: share a6 = reg bit 0 (SB=1)
//  T2 B->C, T3 C->B: share a3 = reg bit 3 (SB=8)
// Compressed 11-bit addresses (shared bit deleted; 2048 F2 = 16 KB):
//  caddrA : [10:6]=r>>1, [5:0]=lane                 (T1 store / T4 load)
//  caddrB1: [10:6]=lane>>1, [5:1]=r>>1, [0]=lane&1  (T1 load  / T4 store)
//  caddrB2: [10:6]=lane>>1, [5]=r&1, [4:3]=r>>4, [2:1]=(r>>1)&3, [0]=lane&1
//                                                   (T2 store / T3 load)
//  caddrC2: [10]=(r>>1)&1, [9]=r&1, [8:3]=lane, [2]=r>>5, [1]=(r>>4)&1,
//           [0]=(r>>2)&1                            (T2 load  / T3 store)
// Swizzle s(a)=a^((a>>6)&15): all 8 patterns give 16 distinct (s&15) values
// x 4 lanes -> conflict-free b64 (free 2-way).

__device__ __forceinline__ int caddrA (int r, int t) { return ((r >> 1) << 6) | t; }
__device__ __forceinline__ int caddrB1(int r, int t) { return ((t >> 1) << 6) | (r & 62) | (t & 1); }
__device__ __forceinline__ int caddrB2(int r, int t) {
    return ((t >> 1) << 6) | ((r & 1) << 5) | (((r >> 4) & 3) << 3)
         | (((r >> 1) & 3) << 1) | (t & 1);
}
__device__ __forceinline__ int caddrC2(int r, int t) {
    return (((r >> 1) & 1) << 10) | ((r & 1) << 9) | (t << 3)
         | (((r >> 5) & 1) << 2) | (((r >> 4) & 1) << 1) | ((r >> 2) & 1);
}
__device__ __forceinline__ int swz(int a) { return a ^ ((a >> 6) & 15); }

// ---- packed fp32 complex primitives (VOP3P) — proven R8-R14 ----
__device__ __forceinline__ F2 pk_mul_bl(F2 a, F2 u) {   // (a.x*u.x, a.y*u.x)
    F2 d;
    asm("v_pk_mul_f32 %0, %1, %2 op_sel:[0,0] op_sel_hi:[1,0]"
        : "=v"(d) : "v"(a), "v"(u));
    return d;
}
__device__ __forceinline__ void pk_cross(F2& d, F2 a, F2 u) {  // d += (-a.y*u.y, a.x*u.y)
    asm("v_pk_fma_f32 %0, %1, %2, %0 op_sel:[1,1,0] op_sel_hi:[0,1,1] neg_lo:[1,0,0]"
        : "+v"(d) : "v"(a), "v"(u));
}
__device__ __forceinline__ void pk_fma_bl(F2& d, F2 a, F2 u) { // d += (a.x*u.x, a.y*u.x)
    asm("v_pk_fma_f32 %0, %1, %2, %0 op_sel:[0,0,0] op_sel_hi:[1,0,1]"
        : "+v"(d) : "v"(a), "v"(u));
}
__device__ __forceinline__ void pk_swapneg(F2& d, F2 a, F2 cs) { // d += (a.y*cs.y, -a.x*cs.y)
    asm("v_pk_fma_f32 %0, %1, %2, %0 op_sel:[1,1,0] op_sel_hi:[0,1,1] neg_hi:[1,0,0]"
        : "+v"(d) : "v"(a), "v"(cs));
}
__device__ __forceinline__ void pk_fma(F2& d, F2 a, F2 b) {    // d += a*b
    asm("v_pk_fma_f32 %0, %1, %2, %0" : "+v"(d) : "v"(a), "v"(b));
}
__device__ __forceinline__ void pk_imacc(F2& d, F2 a0, F2 a1) { // d += (a0.x*a1.y, -a0.y*a1.x)
    asm("v_pk_fma_f32 %0, %1, %2, %0 op_sel:[0,1,0] op_sel_hi:[1,0,1] neg_hi:[1,0,0]"
        : "+v"(d) : "v"(a0), "v"(a1));
}
__device__ __forceinline__ F2 pk_cmul(F2 u, F2 a) {
    F2 d = pk_mul_bl(a, u);
    pk_cross(d, a, u);
    return d;
}
__device__ __forceinline__ void pk_cfma(F2& d, F2 u, F2 a) {
    pk_fma_bl(d, a, u);
    pk_cross(d, a, u);
}

__device__ __forceinline__ void build_u(float tx, float ty, float tz, float* u) {
    float sx = sinf(0.5f*tx), cx = cosf(0.5f*tx);
    float sy = sinf(0.5f*ty), cy = cosf(0.5f*ty);
    float sz = sinf(0.5f*tz), cz = cosf(0.5f*tz);
    float A00r = cy*cx, A00i =  sy*sx;     // A = Ry*Rx
    float A01r = -sy*cx, A01i = -cy*sx;
    float A10r =  sy*cx, A10i = -cy*sx;
    float A11r =  cy*cx, A11i = -sy*sx;
    // U = Rz*A: row0 *= (cz - i sz), row1 *= (cz + i sz)   [verified r1/3/5..14]
    u[0] = cz*A00r + sz*A00i;  u[1] = cz*A00i - sz*A00r;
    u[2] = cz*A01r + sz*A01i;  u[3] = cz*A01i - sz*A01r;
    u[4] = cz*A10r - sz*A10i;  u[5] = cz*A10i + sz*A10r;
    u[6] = cz*A11r - sz*A11i;  u[7] = cz*A11i + sz*A11r;
}

// coef layout (floats): [0..95] U0 plain (q*8); [96..191] RX(ang[36+q-1])*U0[q] (q=1..11);
// [192..287] U1 plain; [288..295] U1[0]*RX(ang[47]); [296..319] L1 CRX (cos,sin)[c=0..11]
__global__ void prep_kernel(const float* __restrict__ ang, float* __restrict__ coef) {
    int t = threadIdx.x;
    if (t < 12) {
        float u[8]; build_u(ang[t], ang[12+t], ang[24+t], u);
#pragma unroll
        for (int j = 0; j < 8; ++j) coef[t*8 + j] = u[j];
    } else if (t < 24) {
        int q = t - 12;
        float u[8]; build_u(ang[48+q], ang[60+q], ang[72+q], u);
#pragma unroll
        for (int j = 0; j < 8; ++j) coef[192 + q*8 + j] = u[j];
    } else if (t < 36) {
        int c = t - 24;
        float th = 0.5f * ang[95 - c];     // L1 ring gate (c,c+1) = tape slot 84+(11-c)
        coef[296 + c*2]     = cosf(th);
        coef[296 + c*2 + 1] = sinf(th);
    } else if (t < 47) {
        int q = t - 35;                    // 1..11: M = RX(ang[36+q-1]) * U0[q]
        float u[8]; build_u(ang[q], ang[12+q], ang[24+q], u);
        float c = cosf(0.5f*ang[36+q-1]), s = sinf(0.5f*ang[36+q-1]);
        float m[8];
        m[0] = c*u[0] + s*u[5];  m[1] = c*u[1] - s*u[4];   // M00 = c u00 - i s u10
        m[2] = c*u[2] + s*u[7];  m[3] = c*u[3] - s*u[6];   // M01 = c u01 - i s u11
        m[4] = s*u[1] + c*u[4];  m[5] = -s*u[0] + c*u[5];  // M10 = -i s u00 + c u10
        m[6] = s*u[3] + c*u[6];  m[7] = -s*u[2] + c*u[7];  // M11 = -i s u01 + c u11
#pragma unroll
        for (int j = 0; j < 8; ++j) coef[96 + q*8 + j] = m[j];
    } else if (t == 47) {                  // M = U1[0] * RX(ang[47])  [CR0(11,0) then U1(0)]
        float u[8]; build_u(ang[48], ang[60], ang[72], u);
        float c = cosf(0.5f*ang[47]), s = sinf(0.5f*ang[47]);
        float m[8];
        m[0] = c*u[0] + s*u[3];  m[1] = c*u[1] - s*u[2];   // M00 = c u00 - i s u01
        m[2] = s*u[1] + c*u[2];  m[3] = -s*u[0] + c*u[3];  // M01 = -i s u00 + c u01
        m[4] = c*u[4] + s*u[7];  m[5] = c*u[5] - s*u[6];   // M10 = c u10 - i s u11
        m[6] = s*u[5] + c*u[6];  m[7] = -s*u[4] + c*u[7];  // M11 = -i s u10 + c u11
#pragma unroll
        for (int j = 0; j < 8; ++j) coef[288 + j] = m[j];
    }
}

// SB != 0 restricts processing to pairs with (r0 & SB) == HB (half-gates that
// fill the split-transpose store windows). SB is never equal to M.
template<int M, int SB, int HB>
__device__ __forceinline__ void g1q(F2* amp, const float* __restrict__ u) {
    F2 u00 = {u[0], u[1]}, u01 = {u[2], u[3]};
    F2 u10 = {u[4], u[5]}, u11 = {u[6], u[7]};
#pragma unroll
    for (int r0 = 0; r0 < 64; ++r0) {
        if (r0 & M) continue;
        if (SB != 0 && (r0 & SB) != HB) continue;
        const int r1 = r0 + M;
        F2 a0 = amp[r0], a1 = amp[r1];
        F2 n0 = pk_cmul(u00, a0); pk_cfma(n0, u01, a1);
        F2 n1 = pk_cmul(u10, a0); pk_cfma(n1, u11, a1);
        amp[r0] = n0; amp[r1] = n1;
    }
}

template<int MSEL, int M, int SB, int HB>   // matrix selected by control bit MSEL
__device__ __forceinline__ void fg1q(F2* amp, const float* __restrict__ uA,
                                     const float* __restrict__ uB) {
    F2 a00 = {uA[0], uA[1]}, a01 = {uA[2], uA[3]}, a10 = {uA[4], uA[5]}, a11 = {uA[6], uA[7]};
    F2 b00 = {uB[0], uB[1]}, b01 = {uB[2], uB[3]}, b10 = {uB[4], uB[5]}, b11 = {uB[6], uB[7]};
#pragma unroll
    for (int r0 = 0; r0 < 64; ++r0) {
        if (r0 & M) continue;
        if (SB != 0 && (r0 & SB) != HB) continue;
        const int r1 = r0 + M;
        const bool sel = (r0 & MSEL) != 0;           // compile-time
        F2 u00 = sel ? b00 : a00, u01 = sel ? b01 : a01;
        F2 u10 = sel ? b10 : a10, u11 = sel ? b11 : a11;
        F2 a0 = amp[r0], a1 = amp[r1];
        F2 n0 = pk_cmul(u00, a0); pk_cfma(n0, u01, a1);
        F2 n1 = pk_cmul(u10, a0); pk_cfma(n1, u11, a1);
        amp[r0] = n0; amp[r1] = n1;
    }
}

template<int MC, int MT>
__device__ __forceinline__ void crx(F2* amp, F2 cs) {
#pragma unroll
    for (int r0 = 0; r0 < 64; ++r0) {
        if (!(r0 & MC) || (r0 & MT)) continue;
        const int r1 = r0 + MT;
        F2 a0 = amp[r0], a1 = amp[r1];
        F2 n0 = pk_mul_bl(a0, cs); pk_swapneg(n0, a1, cs);
        F2 n1 = pk_mul_bl(a1, cs); pk_swapneg(n1, a0, cs);
        amp[r0] = n0; amp[r1] = n1;
    }
}

template<int M>
__device__ __forceinline__ void expv(const F2* amp, int q, int lane,
                                     float& fx, float& fy, float& fz) {
    F2 zp = {0.f, 0.f}, zm = {0.f, 0.f}, xp = {0.f, 0.f}, ip = {0.f, 0.f};
#pragma unroll
    for (int r0 = 0; r0 < 64; ++r0) {
        if (r0 & M) continue;
        const int r1 = r0 + M;
        F2 a0 = amp[r0], a1 = amp[r1];
        pk_fma(zp, a0, a0);
        pk_fma(zm, a1, a1);
        pk_fma(xp, a0, a1);
        pk_imacc(ip, a0, a1);
    }
    float zz = (zp.x + zp.y) - (zm.x + zm.y);
    float xr = 2.f * (xp.x + xp.y);
    float xi = 2.f * (ip.x + ip.y);
#pragma unroll
    for (int off = 32; off; off >>= 1) {
        xr += __shfl_xor(xr, off);
        xi += __shfl_xor(xi, off);
        zz += __shfl_xor(zz, off);
    }
    if (lane == q) { fx = xr; fy = xi; fz = zz; }
}

// enumerate j-th pair base r0 with (r0 & M)==0 and (r0 & SB)==hb*SB (6-bit regs)
template<int M, int SB>
__device__ __forceinline__ int r0_of(int j, int hb) {
    int r = hb ? SB : 0, b = 1;
#pragma unroll
    for (int p = 0; p < 6; ++p) {
        const int mm = 1 << p;
        if (mm == M || mm == SB) continue;
        if (j & b) r |= mm;
        b <<= 1;
    }
    return r;
}

// Store one half (32 regs with (r & SB) == HB); order irrelevant for drain.
#define ST_H(CADDR, SB, HB) \
  { _Pragma("unroll") for (int r = 0; r < 64; ++r) { \
      if ((r & (SB)) != (HB)) continue; \
      psi[swz(CADDR(r, t))] = amp[r]; } }
// Load one half in pair order of the next gate (mask M).
#define LD_H(CADDR, M, SB, HB) \
  { _Pragma("unroll") for (int k = 0; k < 32; ++k) { \
      const int j = k >> 1; \
      const int r0 = r0_of<M, SB>(j, (HB) != 0); \
      const int r = (k & 1) ? (r0 + (M)) : r0; \
      amp[r] = psi[swz(CADDR(r, t))]; } }

#define U0P(q, M)               g1q<M, 0, 0>(amp, cf + (q)*8)
#define FU0(q, MS, M)           fg1q<MS, M, 0, 0>(amp, cf + (q)*8, cf + 96 + (q)*8)
#define FU0_H(q, MS, M, SB, HB) fg1q<MS, M, SB, HB>(amp, cf + (q)*8, cf + 96 + (q)*8)
#define U1P(q, M)               g1q<M, 0, 0>(amp, cf + 192 + (q)*8)
#define U1P_H(q, M, SB, HB)     g1q<M, SB, HB>(amp, cf + 192 + (q)*8)
#define FU1_0()                 fg1q<4, 2, 0, 0>(amp, cf + 192, cf + 288)
#define CR1(c, MC, MT)          crx<MC, MT>(amp, F2{cf[296 + (c)*2], cf[296 + (c)*2 + 1]})
#define EXPV(q, M)              expv<M>(amp, q, t, fx, fy, fz)

__global__ __launch_bounds__(64, 1)
void qsim_kernel(const float* __restrict__ sv,      // [B, 4096]
                 const float* __restrict__ cf,      // [320] precomputed coefficients
                 const float* __restrict__ W,       // [10, 36]
                 const float* __restrict__ bvec,    // [10]
                 float* __restrict__ out)           // [B, 10]
{
    __shared__ F2 psi[2048];         // 16 KB split-transpose buffer
    const int t = threadIdx.x;       // lane 0..63 (single wave)
    const int b = blockIdx.x;

    F2 amp[64];
    const float* svb = sv + (size_t)b * DIM;
    // layout A, coalesced; pair order for U0P(0, M=32)
#pragma unroll
    for (int k = 0; k < 64; ++k) {
        const int r = (k & 1) ? ((k >> 1) + 32) : (k >> 1);
        amp[r] = make_float2(svb[(r << 6) | t], 0.f);
    }

    float fx = 0.f, fy = 0.f, fz = 0.f;

    // ---- A {q0:32 q1:16 q2:8 q3:4 q4:2 q5:1}: U0(0); [U0(q);CR0(q-1,q)] q=1..5 ----
    U0P(0, 32);
    FU0(1, 32, 16); FU0(2, 16, 8); FU0(3, 8, 4); FU0(4, 4, 2); FU0(5, 2, 1);

    // ---- T1: A->B on a6 (reg bit 0 both sides); first B gate FU0(6, MSEL=1, M=32) ----
    ST_H(caddrA, 1, 0);
    __syncthreads();                 // single-wave: lgkmcnt drain (ST->LD RAW)
    LD_H(caddrB1, 32, 1, 0);
    __syncthreads();                 // LD->ST WAR on buffer reuse
    ST_H(caddrA, 1, 1);
    FU0_H(6, 1, 32, 1, 0);           // half-gate on loaded regs fills store window
    __syncthreads();
    LD_H(caddrB1, 32, 1, 1);
    FU0_H(6, 1, 32, 1, 1);

    // ---- B {q5:1 q6:32 q7:16 q8:8 q9:4 q10:2}: [U0(q);CR0(q-1,q)] q=7..10 ----
    FU0(7, 32, 16); FU0(8, 16, 8); FU0(9, 8, 4); FU0(10, 4, 2);

    // ---- T2: B->C on a3 (reg bit 3 both); first C gate FU0(11, MSEL=16, M=4) ----
    __syncthreads();
    ST_H(caddrB2, 8, 0);
    __syncthreads();
    LD_H(caddrC2, 4, 8, 0);
    __syncthreads();
    ST_H(caddrB2, 8, 8);
    FU0_H(11, 16, 4, 8, 0);
    __syncthreads();
    LD_H(caddrC2, 4, 8, 8);
    FU0_H(11, 16, 4, 8, 8);

    // ---- C {q8:8 q9:32 q10:16 q11:4 q0:2 q1:1}: [CR0(11,0);U1(0)]; U1(1,8..11);
    //      L1 ring (11,0),(10,11),(9,10),(8,9); expv 9,10,11 ----
    FU1_0();
    U1P(1, 1); U1P(8, 8); U1P(9, 32); U1P(10, 16); U1P(11, 4);
    CR1(11, 4, 2); CR1(10, 16, 4); CR1(9, 32, 16); CR1(8, 8, 32);

    // ---- T3: C->B on a3; first B' gate U1P(5, M=1) ----
    __syncthreads();
    ST_H(caddrC2, 8, 0);
    EXPV(9, 32); EXPV(10, 16); EXPV(11, 4);   // reads amp only — fills store drain
    __syncthreads();
    LD_H(caddrB2, 1, 8, 0);
    __syncthreads();
    ST_H(caddrC2, 8, 8);
    U1P_H(5, 1, 8, 0);
    __syncthreads();
    LD_H(caddrB2, 1, 8, 8);
    U1P_H(5, 1, 8, 8);

    // ---- B' {5..10}: U1(6,7); L1 ring (7,8),(6,7),(5,6); expv 6,7,8 ----
    U1P(6, 32); U1P(7, 16);
    CR1(7, 16, 8); CR1(6, 32, 16); CR1(5, 1, 32);

    // ---- T4: B->A on a6; first A' gate U1P(2, M=8) ----
    __syncthreads();
    ST_H(caddrB1, 1, 0);
    EXPV(6, 32); EXPV(7, 16); EXPV(8, 8);     // fills store drain
    __syncthreads();
    LD_H(caddrA, 8, 1, 0);
    __syncthreads();
    ST_H(caddrB1, 1, 1);
    U1P_H(2, 8, 1, 0);
    __syncthreads();
    LD_H(caddrA, 8, 1, 1);
    U1P_H(2, 8, 1, 1);

    // ---- A' {0..5}: U1(3,4); L1 ring (4,5),(3,4),(2,3),(1,2),(0,1); expv 0..5 ----
    U1P(3, 4); U1P(4, 2);
    CR1(4, 2, 1); CR1(3, 4, 2); CR1(2, 8, 4); CR1(1, 16, 8); CR1(0, 32, 16);
    EXPV(0, 32); EXPV(1, 16); EXPV(2, 8); EXPV(3, 4); EXPV(4, 2); EXPV(5, 1);

    // ---- features -> out (psi dead after T4 loads drain: alias as fbuf) ----
    __syncthreads();
    float* fbuf = (float*)psi;       // [36]
    if (t < 12) {
        fbuf[t]      = fx;
        fbuf[12 + t] = fy;
        fbuf[24 + t] = fz;
    }
    __syncthreads();
    if (t < 10) {
        float a = bvec[t];
#pragma unroll
        for (int f = 0; f < 36; ++f)
            a += W[t * 36 + f] * fbuf[f];
        out[(size_t)b * 10 + t] = a;
    }
}

extern "C" void kernel_launch(void* const* d_in, const int* in_sizes, int n_in,
                              void* d_out, int out_size, void* d_ws, size_t ws_size,
                              hipStream_t stream) {
    const float* sv     = (const float*)d_in[0];
    const float* angles = (const float*)d_in[1];
    const float* W      = (const float*)d_in[2];
    const float* bvec   = (const float*)d_in[3];
    float* out  = (float*)d_out;
    float* coef = (float*)d_ws;      // 320 floats of scratch
    int batch = in_sizes[0] / DIM;   // 2048
    prep_kernel<<<1, 64, 0, stream>>>(angles, coef);
    qsim_kernel<<<batch, 64, 0, stream>>>(sv, coef, W, bvec, out);
}